// Round 1
// baseline (32677.505 us; speedup 1.0000x reference)
//
#include <hip/hip_runtime.h>

#define B_ 256
#define T_ 512
#define V_ 128
#define E_ 128
#define H_ 256
#define FH 1024

#define GROUPS 32
#define RPG 8      // batch rows per group
#define CWG 16     // column-WGs per group
#define UPW 16     // hidden units per WG
#define ZC 64      // z-columns per WG (= UPW * 4 gates)
#define NWG (GROUPS*CWG)   // 512 workgroups

// ---- workspace layout (float offsets) ----
#define SZ_HT   (2*GROUPS*H_*RPG)          // 131072 floats (double-buffered)
#define OFF_HT0 0
#define OFF_HT1 (OFF_HT0 + SZ_HT)
#define OFF_BAR (OFF_HT1 + SZ_HT)          // 64 uint counters (cntA[32], cntB[32])
#define OFF_TP  (OFF_BAR + 64)             // TokProj [V][1024] packed
#define OFF_CP  (OFF_TP + V_*FH)           // ClusProj [B][1024] packed (+b0)
#define OFF_WP0 (OFF_CP + B_*FH)           // W0h packed [16][256][64]
#define OFF_WP1 (OFF_WP0 + H_*FH)          // W1 packed  [16][512][64]
#define OFF_DWT (OFF_WP1 + 2*H_*FH)        // decoderW^T [128][256]
#define OFF_B1  (OFF_DWT + V_*H_)          // b1 packed [1024]

// packed column order: local col = u*4+g  ->  global z-col G = g*256 + c*16 + u
__device__ __forceinline__ int gcol(int c, int col) {
  int u = col >> 2, g = col & 3;
  return g*256 + c*16 + u;
}

__device__ __forceinline__ float sigm(float x){ return 1.f/(1.f+__expf(-x)); }
__device__ __forceinline__ float tanh_(float x){ return 1.f - 2.f/(1.f+__expf(2.f*x)); }

// ============ prep kernels ============

__global__ void prep_pack(const float* __restrict__ W0, const float* __restrict__ W1,
                          const float* __restrict__ dW, const float* __restrict__ b1,
                          float* __restrict__ ws) {
  float* wp0 = ws + OFF_WP0; float* wp1 = ws + OFF_WP1;
  float* dwT = ws + OFF_DWT; float* b1p = ws + OFF_B1;
  const int N0 = CWG*H_*ZC;       // 262144
  const int N1 = CWG*2*H_*ZC;     // 524288
  const int N2 = V_*H_;           // 32768
  const int N3 = FH;              // 1024
  const int total = N0+N1+N2+N3;
  for (int i = blockIdx.x*blockDim.x + threadIdx.x; i < total; i += gridDim.x*blockDim.x) {
    if (i < N0) {
      int c = i / (H_*ZC); int k = (i / ZC) % H_; int col = i % ZC;
      wp0[i] = W0[(E_+H_+k)*FH + gcol(c,col)];          // W0 rows 384..639 (h0)
    } else if (i < N0+N1) {
      int j = i - N0;
      int c = j / (2*H_*ZC); int k = (j / ZC) % (2*H_); int col = j % ZC;
      wp1[j] = W1[k*FH + gcol(c,col)];                  // rows 0..255=h0n, 256..511=h1
    } else if (i < N0+N1+N2) {
      int l = i - N0 - N1;
      int v = l >> 8, k = l & 255;
      dwT[l] = dW[k*V_ + v];
    } else {
      int cc = i - N0 - N1 - N2;
      b1p[cc] = b1[gcol(cc>>6, cc&63)];
    }
  }
}

__global__ void prep_tok(const float* __restrict__ cemb, const float* __restrict__ W0,
                         float* __restrict__ ws) {
  __shared__ float ce[E_];
  float* TP = ws + OFF_TP;
  int v = blockIdx.x >> 2, q = blockIdx.x & 3;
  int tid = threadIdx.x;
  if (tid < E_) ce[tid] = cemb[v*E_ + tid];
  __syncthreads();
  int ccol = q*256 + tid;
  int G = gcol(ccol>>6, ccol&63);
  float acc = 0.f;
  for (int e = 0; e < E_; ++e) acc = fmaf(ce[e], W0[e*FH + G], acc);
  TP[v*FH + ccol] = acc;
}

__global__ void prep_clus(const int* __restrict__ clus, const float* __restrict__ clemb,
                          const float* __restrict__ W0, const float* __restrict__ b0,
                          float* __restrict__ ws) {
  __shared__ float ce[H_];
  float* CP = ws + OFF_CP;
  int b = blockIdx.x >> 2, q = blockIdx.x & 3;
  int tid = threadIdx.x;
  int cl = clus[b];
  ce[tid] = clemb[(long long)cl*H_ + tid];
  __syncthreads();
  int ccol = q*256 + tid;
  int G = gcol(ccol>>6, ccol&63);
  float acc = b0[G];
  for (int e = 0; e < H_; ++e) acc = fmaf(ce[e], W0[(E_+e)*FH + G], acc);
  CP[b*FH + ccol] = acc;
}

// ============ main persistent kernel ============

// z-accumulation: 64 k-steps (this wave's quarter), 8 rows, 1 z-col per lane.
__device__ __forceinline__ void zacc(const float* hp, const float* __restrict__ wp,
                                     int wv, int lane, float a[RPG]) {
  #pragma unroll 4
  for (int kk = 0; kk < 64; ++kk) {
    int k = wv*64 + kk;
    float w = wp[k*ZC + lane];
    float4 hA = *(const float4*)(hp + k*RPG);
    float4 hB = *(const float4*)(hp + k*RPG + 4);
    a[0]=fmaf(hA.x,w,a[0]); a[1]=fmaf(hA.y,w,a[1]);
    a[2]=fmaf(hA.z,w,a[2]); a[3]=fmaf(hA.w,w,a[3]);
    a[4]=fmaf(hB.x,w,a[4]); a[5]=fmaf(hB.y,w,a[5]);
    a[6]=fmaf(hB.z,w,a[6]); a[7]=fmaf(hB.w,w,a[7]);
  }
}

__global__ __launch_bounds__(256, 2) void lstm_persist(
    const int* __restrict__ toks, const int* __restrict__ lens,
    const float* __restrict__ decB, float* ws, float* __restrict__ out)
{
  float* ht0 = ws + OFF_HT0;
  float* ht1 = ws + OFF_HT1;
  unsigned* bar = (unsigned*)(ws + OFF_BAR);
  const float* TP  = ws + OFF_TP;
  const float* CP  = ws + OFF_CP;
  const float* wp0 = ws + OFF_WP0;
  const float* wp1 = ws + OFF_WP1;
  const float* dwT = ws + OFF_DWT;
  const float* b1p = ws + OFF_B1;

  const int wg  = blockIdx.x;
  const int grp = wg >> 4;       // 0..31
  const int c   = wg & 15;       // column-WG 0..15
  const int tid = threadIdx.x;
  const int lane = tid & 63;
  const int wv   = tid >> 6;     // k-quarter of this wave

  __shared__ float zred[4][RPG][ZC];   // 8 KB partial-z reduction
  __shared__ float ldsW[8][260];       // decoderW slice, padded stride (bank spread)
  __shared__ float pred[256];
  __shared__ int   smax;

  // stage decoder weight slice (v = c*8 .. c*8+7)
  for (int i = tid; i < 8*H_; i += 256)
    ldsW[i>>8][i&255] = dwT[(c*8 + (i>>8))*H_ + (i&255)];
  if (tid == 0) {
    int mx = 0;
    for (int r = 0; r < RPG; ++r) mx = max(mx, lens[grp*RPG + r]);
    smax = mx;
  }
  __syncthreads();
  const int Lg = smax;

  // gate-thread state (threads 0..127: tid = m*16+u)
  const int gm = tid >> 4, gu = tid & 15;
  float c0=0.f, h0=0.f, c1=0.f, h1=0.f;
  int mylen = 0; float4 b1v = make_float4(0.f,0.f,0.f,0.f);
  int cpoff = 0;
  if (tid < 128) {
    mylen = lens[grp*RPG + gm];
    b1v = *(const float4*)(b1p + c*64 + gu*4);
    cpoff = (grp*RPG + gm)*FH + c*64 + gu*4;
  }
  // projection-thread constants: tid = kq*64 + m*8 + v
  const int pm = (tid >> 3) & 7;
  const int pv = tid & 7;
  const int pkq = tid >> 6;
  const float pdecb = decB[c*8 + pv];
  const int plen = lens[grp*RPG + pm];

  unsigned* cA = bar + grp;
  unsigned* cB = bar + 32 + grp;

  const int bufstride = GROUPS*H_*RPG;
  const int hbase = grp*H_*RPG;

  int cur = 0;
  float a0[RPG];
  #pragma unroll
  for (int r = 0; r < RPG; ++r) a0[r] = 0.f;   // z0(t=0): h0(-1)=0

  for (int t = 0; t < Lg; ++t) {
    const int prev = cur ^ 1;

    // ---- gates layer 0 ----
    #pragma unroll
    for (int r = 0; r < RPG; ++r) zred[wv][r][lane] = a0[r];
    __syncthreads();
    if (tid < 128) {
      float4 s0 = *(const float4*)&zred[0][gm][gu*4];
      float4 s1 = *(const float4*)&zred[1][gm][gu*4];
      float4 s2 = *(const float4*)&zred[2][gm][gu*4];
      float4 s3 = *(const float4*)&zred[3][gm][gu*4];
      int tok = toks[(grp*RPG + gm)*T_ + t];
      float4 tp = *(const float4*)(TP + tok*FH + c*64 + gu*4);
      float4 cp = *(const float4*)(CP + cpoff);
      float zi = s0.x+s1.x+s2.x+s3.x + tp.x + cp.x;
      float zj = s0.y+s1.y+s2.y+s3.y + tp.y + cp.y;
      float zf = s0.z+s1.z+s2.z+s3.z + tp.z + cp.z;
      float zo = s0.w+s1.w+s2.w+s3.w + tp.w + cp.w;
      float c0n = c0*sigm(zf + 1.f) + sigm(zi)*tanh_(zj);
      float h0n = tanh_(c0n)*sigm(zo);
      if (t < mylen) { c0 = c0n; h0 = h0n; }
      __hip_atomic_store(ht0 + cur*bufstride + hbase + (c*UPW + gu)*RPG + gm, h0,
                         __ATOMIC_RELAXED, __HIP_MEMORY_SCOPE_AGENT);
    }
    __syncthreads();
    if (tid == 0) {
      __builtin_amdgcn_fence(__ATOMIC_RELEASE, "agent");
      atomicAdd(cA, 1u);
    }

    // ---- z1 part 1: h1(t-1) contribution (overlaps barrier A) ----
    float a1[RPG];
    #pragma unroll
    for (int r = 0; r < RPG; ++r) a1[r] = 0.f;
    zacc(ht1 + prev*bufstride + hbase, wp1 + (c*2*H_ + H_)*ZC, wv, lane, a1);

    // wait barrier A (h0(t) published by all 16 WGs of the group)
    if (tid == 0) {
      unsigned tgt = (unsigned)(CWG*(t+1));
      while (__hip_atomic_load(cA, __ATOMIC_RELAXED, __HIP_MEMORY_SCOPE_AGENT) < tgt)
        __builtin_amdgcn_s_sleep(1);
    }
    __syncthreads();
    __builtin_amdgcn_fence(__ATOMIC_ACQUIRE, "agent");

    // ---- z1 part 2: h0(t) contribution ----
    zacc(ht0 + cur*bufstride + hbase, wp1 + (c*2*H_)*ZC, wv, lane, a1);

    // ---- gates layer 1 ----
    #pragma unroll
    for (int r = 0; r < RPG; ++r) zred[wv][r][lane] = a1[r];
    __syncthreads();
    if (tid < 128) {
      float4 s0 = *(const float4*)&zred[0][gm][gu*4];
      float4 s1 = *(const float4*)&zred[1][gm][gu*4];
      float4 s2 = *(const float4*)&zred[2][gm][gu*4];
      float4 s3 = *(const float4*)&zred[3][gm][gu*4];
      float zi = s0.x+s1.x+s2.x+s3.x + b1v.x;
      float zj = s0.y+s1.y+s2.y+s3.y + b1v.y;
      float zf = s0.z+s1.z+s2.z+s3.z + b1v.z;
      float zo = s0.w+s1.w+s2.w+s3.w + b1v.w;
      float c1n = c1*sigm(zf + 1.f) + sigm(zi)*tanh_(zj);
      float h1n = tanh_(c1n)*sigm(zo);
      if (t < mylen) { c1 = c1n; h1 = h1n; }
      __hip_atomic_store(ht1 + cur*bufstride + hbase + (c*UPW + gu)*RPG + gm, h1,
                         __ATOMIC_RELAXED, __HIP_MEMORY_SCOPE_AGENT);
    }
    __syncthreads();
    if (tid == 0) {
      __builtin_amdgcn_fence(__ATOMIC_RELEASE, "agent");
      atomicAdd(cB, 1u);
    }

    // ---- z0 for step t+1 (overlaps barrier B; reads h0(t), synced at A) ----
    if (t + 1 < Lg) {
      #pragma unroll
      for (int r = 0; r < RPG; ++r) a0[r] = 0.f;
      zacc(ht0 + cur*bufstride + hbase, wp0 + c*H_*ZC, wv, lane, a0);
    }

    // wait barrier B (h1(t) published)
    if (tid == 0) {
      unsigned tgt = (unsigned)(CWG*(t+1));
      while (__hip_atomic_load(cB, __ATOMIC_RELAXED, __HIP_MEMORY_SCOPE_AGENT) < tgt)
        __builtin_amdgcn_s_sleep(1);
    }
    __syncthreads();
    __builtin_amdgcn_fence(__ATOMIC_ACQUIRE, "agent");

    // ---- fused output projection: out[b][t][c*8+v] ----
    {
      const float* hp = ht1 + cur*bufstride + hbase;
      float acc = 0.f;
      #pragma unroll 4
      for (int kk = 0; kk < 64; ++kk) {
        int k = pkq*64 + kk;
        acc = fmaf(hp[k*RPG + pm], ldsW[pv][k], acc);
      }
      pred[tid] = acc;
    }
    __syncthreads();
    if (tid < 64) {
      float tot = pred[tid] + pred[tid+64] + pred[tid+128] + pred[tid+192] + pdecb;
      if (t < plen)
        out[((size_t)(grp*RPG + pm)*T_ + t)*V_ + c*8 + pv] = tot;
    }

    cur ^= 1;
  }
}

// ============ launch ============

extern "C" void kernel_launch(void* const* d_in, const int* in_sizes, int n_in,
                              void* d_out, int out_size, void* d_ws, size_t ws_size,
                              hipStream_t stream) {
  const int*   toks  = (const int*)d_in[0];
  const int*   lens  = (const int*)d_in[1];
  const int*   clus  = (const int*)d_in[2];
  const float* cemb  = (const float*)d_in[3];
  const float* clemb = (const float*)d_in[4];
  const float* W0    = (const float*)d_in[5];
  const float* b0    = (const float*)d_in[6];
  const float* W1    = (const float*)d_in[7];
  const float* b1    = (const float*)d_in[8];
  const float* dW    = (const float*)d_in[9];
  const float* decB  = (const float*)d_in[10];
  float* out = (float*)d_out;
  float* ws  = (float*)d_ws;

  // zero output (masked positions must be exactly 0) and h-state + barrier counters
  hipMemsetAsync(out, 0, (size_t)B_*T_*V_*sizeof(float), stream);
  hipMemsetAsync(ws, 0, (size_t)(2*SZ_HT)*sizeof(float) + 256, stream);

  prep_pack<<<1024, 256, 0, stream>>>(W0, W1, dW, b1, ws);
  prep_tok <<<V_*4, 256, 0, stream>>>(cemb, W0, ws);
  prep_clus<<<B_*4, 256, 0, stream>>>(clus, clemb, W0, b0, ws);
  lstm_persist<<<NWG, 256, 0, stream>>>(toks, lens, decB, ws, out);
}

// Round 2
// 29204.898 us; speedup vs baseline: 1.1189x; 1.1189x over previous
//
#include <hip/hip_runtime.h>

#define B_ 256
#define T_ 512
#define V_ 128
#define E_ 128
#define H_ 256
#define FH 1024

#define GROUPS 32
#define RPG 8      // batch rows per group
#define CWG 16     // column-WGs per group
#define UPW 16     // hidden units per WG
#define ZC 64      // z-columns per WG (= UPW * 4 gates)
#define NWG (GROUPS*CWG)   // 512 workgroups

// ---- workspace layout (float offsets) ----
#define SZ_HT   (2*GROUPS*H_*RPG)          // 131072 floats (double-buffered)
#define OFF_HT0 0
#define OFF_HT1 (OFF_HT0 + SZ_HT)
#define OFF_BAR (OFF_HT1 + SZ_HT)          // flag barrier: 32 groups * 128 uints (512B stride)
#define OFF_TP  (OFF_BAR + 4096)           // TokProj [V][1024] packed
#define OFF_CP  (OFF_TP + V_*FH)           // ClusProj [B][1024] packed (+b0)
#define OFF_WP0 (OFF_CP + B_*FH)           // W0h packed [16][256][64]
#define OFF_WP1 (OFF_WP0 + H_*FH)          // W1 packed  [16][512][64]
#define OFF_DWT (OFF_WP1 + 2*H_*FH)        // decoderW^T [128][256]
#define OFF_B1  (OFF_DWT + V_*H_)          // b1 packed [1024]

// packed column order: local col = u*4+g  ->  global z-col G = g*256 + c*16 + u
__device__ __forceinline__ int gcol(int c, int col) {
  int u = col >> 2, g = col & 3;
  return g*256 + c*16 + u;
}

__device__ __forceinline__ float sigm(float x){ return 1.f/(1.f+__expf(-x)); }
__device__ __forceinline__ float tanh_(float x){ return 1.f - 2.f/(1.f+__expf(2.f*x)); }

// ============ prep kernels ============

__global__ void prep_pack(const float* __restrict__ W0, const float* __restrict__ W1,
                          const float* __restrict__ dW, const float* __restrict__ b1,
                          float* __restrict__ ws) {
  float* wp0 = ws + OFF_WP0; float* wp1 = ws + OFF_WP1;
  float* dwT = ws + OFF_DWT; float* b1p = ws + OFF_B1;
  const int N0 = CWG*H_*ZC;       // 262144
  const int N1 = CWG*2*H_*ZC;     // 524288
  const int N2 = V_*H_;           // 32768
  const int N3 = FH;              // 1024
  const int total = N0+N1+N2+N3;
  for (int i = blockIdx.x*blockDim.x + threadIdx.x; i < total; i += gridDim.x*blockDim.x) {
    if (i < N0) {
      int c = i / (H_*ZC); int k = (i / ZC) % H_; int col = i % ZC;
      wp0[i] = W0[(E_+H_+k)*FH + gcol(c,col)];          // W0 rows 384..639 (h0)
    } else if (i < N0+N1) {
      int j = i - N0;
      int c = j / (2*H_*ZC); int k = (j / ZC) % (2*H_); int col = j % ZC;
      wp1[j] = W1[k*FH + gcol(c,col)];                  // rows 0..255=h0n, 256..511=h1
    } else if (i < N0+N1+N2) {
      int l = i - N0 - N1;
      int v = l >> 8, k = l & 255;
      dwT[l] = dW[k*V_ + v];
    } else {
      int cc = i - N0 - N1 - N2;
      b1p[cc] = b1[gcol(cc>>6, cc&63)];
    }
  }
}

__global__ void prep_tok(const float* __restrict__ cemb, const float* __restrict__ W0,
                         float* __restrict__ ws) {
  __shared__ float ce[E_];
  float* TP = ws + OFF_TP;
  int v = blockIdx.x >> 2, q = blockIdx.x & 3;
  int tid = threadIdx.x;
  if (tid < E_) ce[tid] = cemb[v*E_ + tid];
  __syncthreads();
  int ccol = q*256 + tid;
  int G = gcol(ccol>>6, ccol&63);
  float acc = 0.f;
  for (int e = 0; e < E_; ++e) acc = fmaf(ce[e], W0[e*FH + G], acc);
  TP[v*FH + ccol] = acc;
}

__global__ void prep_clus(const int* __restrict__ clus, const float* __restrict__ clemb,
                          const float* __restrict__ W0, const float* __restrict__ b0,
                          float* __restrict__ ws) {
  __shared__ float ce[H_];
  float* CP = ws + OFF_CP;
  int b = blockIdx.x >> 2, q = blockIdx.x & 3;
  int tid = threadIdx.x;
  int cl = clus[b];
  ce[tid] = clemb[(long long)cl*H_ + tid];
  __syncthreads();
  int ccol = q*256 + tid;
  int G = gcol(ccol>>6, ccol&63);
  float acc = b0[G];
  for (int e = 0; e < H_; ++e) acc = fmaf(ce[e], W0[(E_+e)*FH + G], acc);
  CP[b*FH + ccol] = acc;
}

// ============ main persistent kernel ============

// z-accumulation: 64 k-steps (this wave's quarter), 8 rows, 1 z-col per lane.
__device__ __forceinline__ void zacc(const float* hp, const float* __restrict__ wp,
                                     int wv, int lane, float a[RPG]) {
  #pragma unroll 4
  for (int kk = 0; kk < 64; ++kk) {
    int k = wv*64 + kk;
    float w = wp[k*ZC + lane];
    float4 hA = *(const float4*)(hp + k*RPG);
    float4 hB = *(const float4*)(hp + k*RPG + 4);
    a[0]=fmaf(hA.x,w,a[0]); a[1]=fmaf(hA.y,w,a[1]);
    a[2]=fmaf(hA.z,w,a[2]); a[3]=fmaf(hA.w,w,a[3]);
    a[4]=fmaf(hB.x,w,a[4]); a[5]=fmaf(hB.y,w,a[5]);
    a[6]=fmaf(hB.z,w,a[6]); a[7]=fmaf(hB.w,w,a[7]);
  }
}

// all-thread spin on the group's 16 per-WG flag slots (one 64B line)
__device__ __forceinline__ void flag_wait(const unsigned* f, int lane, unsigned tgt) {
  const unsigned* p = f + (lane & 15);
  for (;;) {
    unsigned v = __hip_atomic_load(p, __ATOMIC_RELAXED, __HIP_MEMORY_SCOPE_AGENT);
    if (__all((int)(v >= tgt))) break;
    __builtin_amdgcn_s_sleep(1);
  }
  __builtin_amdgcn_fence(__ATOMIC_ACQUIRE, "agent");
}

__global__ __launch_bounds__(256, 2) void lstm_persist(
    const int* __restrict__ toks, const int* __restrict__ lens,
    const float* __restrict__ decB, float* ws, float* __restrict__ out)
{
  float* ht0 = ws + OFF_HT0;
  float* ht1 = ws + OFF_HT1;
  unsigned* flags = (unsigned*)(ws + OFF_BAR);
  const float* TP  = ws + OFF_TP;
  const float* CP  = ws + OFF_CP;
  const float* wp0 = ws + OFF_WP0;
  const float* wp1 = ws + OFF_WP1;
  const float* dwT = ws + OFF_DWT;
  const float* b1p = ws + OFF_B1;

  // XCD-colocation swizzle: consecutive blockIdx round-robin across 8 XCDs
  // (MI300-series dispatch heuristic; correctness-neutral). xcd = blk&7,
  // slot = blk>>3 (0..63 per XCD) -> 4 whole groups per XCD.
  const int blk  = blockIdx.x;
  const int grp  = ((blk & 7) << 2) | ((blk >> 3) >> 4);  // 0..31
  const int c    = (blk >> 3) & 15;                        // column-WG 0..15
  const int tid  = threadIdx.x;
  const int lane = tid & 63;
  const int wv   = tid >> 6;     // k-quarter of this wave

  __shared__ float zred[4][RPG][ZC];   // 8 KB partial-z reduction
  __shared__ float ldsW[8][260];       // decoderW slice, padded stride
  __shared__ float pred[256];
  __shared__ int   smax;

  // stage decoder weight slice (v = c*8 .. c*8+7)
  for (int i = tid; i < 8*H_; i += 256)
    ldsW[i>>8][i&255] = dwT[(c*8 + (i>>8))*H_ + (i&255)];
  if (tid == 0) {
    int mx = 0;
    for (int r = 0; r < RPG; ++r) mx = max(mx, lens[grp*RPG + r]);
    smax = mx;
  }
  __syncthreads();
  const int Lg = smax;

  // gate-thread state (threads 0..127: tid = m*16+u)
  const int gm = tid >> 4, gu = tid & 15;
  float c0=0.f, h0=0.f, c1=0.f, h1=0.f;
  int mylen = 0; float4 b1v = make_float4(0.f,0.f,0.f,0.f);
  int cpoff = 0;
  if (tid < 128) {
    mylen = lens[grp*RPG + gm];
    b1v = *(const float4*)(b1p + c*64 + gu*4);
    cpoff = (grp*RPG + gm)*FH + c*64 + gu*4;
  }
  // projection-thread constants: tid = kq*64 + m*8 + v
  const int pm = (tid >> 3) & 7;
  const int pv = tid & 7;
  const int pkq = tid >> 6;
  const float pdecb = decB[c*8 + pv];
  const int plen = lens[grp*RPG + pm];

  unsigned* fA = flags + grp*128;        // 16 slots, one 64B line
  unsigned* fB = fA + 32;                // 128B away, same group block

  const int bufstride = GROUPS*H_*RPG;
  const int hbase = grp*H_*RPG;

  int cur = 0;
  float a0[RPG];
  #pragma unroll
  for (int r = 0; r < RPG; ++r) a0[r] = 0.f;   // z0(t=0): h0(-1)=0

  for (int t = 0; t < Lg; ++t) {
    const int prev = cur ^ 1;
    const unsigned tgt = (unsigned)(t + 1);

    // ---- gates layer 0 ----
    #pragma unroll
    for (int r = 0; r < RPG; ++r) zred[wv][r][lane] = a0[r];
    __syncthreads();
    if (tid < 128) {
      float4 s0 = *(const float4*)&zred[0][gm][gu*4];
      float4 s1 = *(const float4*)&zred[1][gm][gu*4];
      float4 s2 = *(const float4*)&zred[2][gm][gu*4];
      float4 s3 = *(const float4*)&zred[3][gm][gu*4];
      int tok = toks[(grp*RPG + gm)*T_ + t];
      float4 tp = *(const float4*)(TP + tok*FH + c*64 + gu*4);
      float4 cp = *(const float4*)(CP + cpoff);
      float zi = s0.x+s1.x+s2.x+s3.x + tp.x + cp.x;
      float zj = s0.y+s1.y+s2.y+s3.y + tp.y + cp.y;
      float zf = s0.z+s1.z+s2.z+s3.z + tp.z + cp.z;
      float zo = s0.w+s1.w+s2.w+s3.w + tp.w + cp.w;
      float c0n = c0*sigm(zf + 1.f) + sigm(zi)*tanh_(zj);
      float h0n = tanh_(c0n)*sigm(zo);
      if (t < mylen) { c0 = c0n; h0 = h0n; }
      __hip_atomic_store(ht0 + cur*bufstride + hbase + (c*UPW + gu)*RPG + gm, h0,
                         __ATOMIC_RELAXED, __HIP_MEMORY_SCOPE_AGENT);
    }
    __syncthreads();                      // drains the h0 stores (vmcnt0 before barrier)
    if (tid == 0) {
      __builtin_amdgcn_fence(__ATOMIC_RELEASE, "agent");
      __hip_atomic_store(fA + c, tgt, __ATOMIC_RELAXED, __HIP_MEMORY_SCOPE_AGENT);
    }

    // ---- z1 part 1: h1(t-1) contribution (overlaps barrier A) ----
    float a1[RPG];
    #pragma unroll
    for (int r = 0; r < RPG; ++r) a1[r] = 0.f;
    zacc(ht1 + prev*bufstride + hbase, wp1 + (c*2*H_ + H_)*ZC, wv, lane, a1);

    // wait barrier A (h0(t) published by all 16 WGs of the group)
    flag_wait(fA, lane, tgt);

    // ---- z1 part 2: h0(t) contribution ----
    zacc(ht0 + cur*bufstride + hbase, wp1 + (c*2*H_)*ZC, wv, lane, a1);

    // ---- gates layer 1 ----
    #pragma unroll
    for (int r = 0; r < RPG; ++r) zred[wv][r][lane] = a1[r];
    __syncthreads();
    if (tid < 128) {
      float4 s0 = *(const float4*)&zred[0][gm][gu*4];
      float4 s1 = *(const float4*)&zred[1][gm][gu*4];
      float4 s2 = *(const float4*)&zred[2][gm][gu*4];
      float4 s3 = *(const float4*)&zred[3][gm][gu*4];
      float zi = s0.x+s1.x+s2.x+s3.x + b1v.x;
      float zj = s0.y+s1.y+s2.y+s3.y + b1v.y;
      float zf = s0.z+s1.z+s2.z+s3.z + b1v.z;
      float zo = s0.w+s1.w+s2.w+s3.w + b1v.w;
      float c1n = c1*sigm(zf + 1.f) + sigm(zi)*tanh_(zj);
      float h1n = tanh_(c1n)*sigm(zo);
      if (t < mylen) { c1 = c1n; h1 = h1n; }
      __hip_atomic_store(ht1 + cur*bufstride + hbase + (c*UPW + gu)*RPG + gm, h1,
                         __ATOMIC_RELAXED, __HIP_MEMORY_SCOPE_AGENT);
    }
    __syncthreads();
    if (tid == 0) {
      __builtin_amdgcn_fence(__ATOMIC_RELEASE, "agent");
      __hip_atomic_store(fB + c, tgt, __ATOMIC_RELAXED, __HIP_MEMORY_SCOPE_AGENT);
    }

    // ---- z0 for step t+1 (overlaps barrier B; reads h0(t), synced at A) ----
    if (t + 1 < Lg) {
      #pragma unroll
      for (int r = 0; r < RPG; ++r) a0[r] = 0.f;
      zacc(ht0 + cur*bufstride + hbase, wp0 + c*H_*ZC, wv, lane, a0);
    }

    // wait barrier B (h1(t) published)
    flag_wait(fB, lane, tgt);

    // ---- fused output projection: out[b][t][c*8+v] ----
    {
      const float* hp = ht1 + cur*bufstride + hbase;
      float acc = 0.f;
      #pragma unroll 4
      for (int kk = 0; kk < 64; ++kk) {
        int k = pkq*64 + kk;
        acc = fmaf(hp[k*RPG + pm], ldsW[pv][k], acc);
      }
      pred[tid] = acc;
    }
    __syncthreads();
    if (tid < 64) {
      float tot = pred[tid] + pred[tid+64] + pred[tid+128] + pred[tid+192] + pdecb;
      if (t < plen)
        out[((size_t)(grp*RPG + pm)*T_ + t)*V_ + c*8 + pv] = tot;
    }

    cur ^= 1;
  }
}

// ============ launch ============

extern "C" void kernel_launch(void* const* d_in, const int* in_sizes, int n_in,
                              void* d_out, int out_size, void* d_ws, size_t ws_size,
                              hipStream_t stream) {
  const int*   toks  = (const int*)d_in[0];
  const int*   lens  = (const int*)d_in[1];
  const int*   clus  = (const int*)d_in[2];
  const float* cemb  = (const float*)d_in[3];
  const float* clemb = (const float*)d_in[4];
  const float* W0    = (const float*)d_in[5];
  const float* b0    = (const float*)d_in[6];
  const float* W1    = (const float*)d_in[7];
  const float* b1    = (const float*)d_in[8];
  const float* dW    = (const float*)d_in[9];
  const float* decB  = (const float*)d_in[10];
  float* out = (float*)d_out;
  float* ws  = (float*)d_ws;

  // zero output (masked positions must be exactly 0) and h-state + barrier flags
  hipMemsetAsync(out, 0, (size_t)B_*T_*V_*sizeof(float), stream);
  hipMemsetAsync(ws, 0, (size_t)(2*SZ_HT)*sizeof(float) + 4096*sizeof(unsigned), stream);

  prep_pack<<<1024, 256, 0, stream>>>(W0, W1, dW, b1, ws);
  prep_tok <<<V_*4, 256, 0, stream>>>(cemb, W0, ws);
  prep_clus<<<B_*4, 256, 0, stream>>>(clus, clemb, W0, b0, ws);
  lstm_persist<<<NWG, 256, 0, stream>>>(toks, lens, decB, ws, out);
}

// Round 5
// 18409.065 us; speedup vs baseline: 1.7751x; 1.5864x over previous
//
#include <hip/hip_runtime.h>

#define B_ 256
#define T_ 512
#define V_ 128
#define E_ 128
#define H_ 256
#define FH 1024

#define GROUPS 32
#define RPG 8      // batch rows per group
#define CWG 16     // column-WGs per group
#define NWG (GROUPS*CWG)

typedef float f4 __attribute__((ext_vector_type(4)));

// ---- workspace layout (float offsets) ----
#define OFF_HT0  0                              // h0 [grp][256k][8rows]  (single-buffered, see proof in notes)
#define OFF_HT1  (OFF_HT0 + GROUPS*H_*RPG)      // h1 same layout
#define OFF_BAR  (OFF_HT1 + GROUPS*H_*RPG)      // 32 groups * 128 uints (512B stride)
#define OFF_TP   (OFF_BAR + 4096)               // TokProj [V][1024] packed
#define OFF_CP   (OFF_TP + V_*FH)               // ClusProj [B][1024] packed (+b0)
#define OFF_WP0  (OFF_CP + B_*FH)               // W0h x4-packed [16c][64kb][64lane][4j]
#define OFF_WP1  (OFF_WP0 + CWG*64*64*4)        // W1  x4-packed [16c][128kb][64lane][4j]
#define OFF_DWT  (OFF_WP1 + CWG*128*64*4)       // decoderW^T [128v][256k]
#define OFF_B1   (OFF_DWT + V_*H_)              // b1 packed [1024]

// packed column order: local col = u*4+g  ->  global z-col G = g*256 + c*16 + u
__device__ __forceinline__ int gcol(int c, int col) {
  int u = col >> 2, g = col & 3;
  return g*256 + c*16 + u;
}

__device__ __forceinline__ float sigm(float x){ return 1.f/(1.f+__expf(-x)); }
__device__ __forceinline__ float tanh_(float x){ return 1.f - 2.f/(1.f+__expf(2.f*x)); }

// ============ prep kernels ============

__global__ void prep_pack(const float* __restrict__ W0, const float* __restrict__ W1,
                          const float* __restrict__ dW, const float* __restrict__ b1,
                          float* __restrict__ ws) {
  float* wp0 = ws + OFF_WP0; float* wp1 = ws + OFF_WP1;
  float* dwT = ws + OFF_DWT; float* b1p = ws + OFF_B1;
  const int N0 = CWG*64*64*4;     // 262144
  const int N1 = CWG*128*64*4;    // 524288
  const int N2 = V_*H_;           // 32768
  const int N3 = FH;              // 1024
  const int total = N0+N1+N2+N3;
  for (int i = blockIdx.x*blockDim.x + threadIdx.x; i < total; i += gridDim.x*blockDim.x) {
    if (i < N0) {
      int cc = i >> 14; int rem = i & 16383;
      int kb = rem >> 8; int ln = (rem >> 2) & 63; int j = i & 3;
      int k = kb*4 + j;
      wp0[i] = W0[(E_+H_+k)*FH + gcol(cc, ln)];          // W0 h0-rows
    } else if (i < N0+N1) {
      int idx = i - N0;
      int cc = idx >> 15; int rem = idx & 32767;
      int kb = rem >> 8; int ln = (rem >> 2) & 63; int j = idx & 3;
      int k2 = kb*4 + j;                                  // 0..255 h0n, 256..511 h1
      wp1[idx] = W1[k2*FH + gcol(cc, ln)];
    } else if (i < N0+N1+N2) {
      int l = i - N0 - N1;
      int v = l >> 8, k = l & 255;
      dwT[l] = dW[k*V_ + v];
    } else {
      int cc2 = i - N0 - N1 - N2;
      b1p[cc2] = b1[gcol(cc2>>6, cc2&63)];
    }
  }
}

__global__ void prep_tok(const float* __restrict__ cemb, const float* __restrict__ W0,
                         float* __restrict__ ws) {
  __shared__ float ce[E_];
  float* TP = ws + OFF_TP;
  int v = blockIdx.x >> 2, q = blockIdx.x & 3;
  int tid = threadIdx.x;
  if (tid < E_) ce[tid] = cemb[v*E_ + tid];
  __syncthreads();
  int ccol = q*256 + tid;
  int G = gcol(ccol>>6, ccol&63);
  float acc = 0.f;
  for (int e = 0; e < E_; ++e) acc = fmaf(ce[e], W0[e*FH + G], acc);
  TP[v*FH + ccol] = acc;
}

__global__ void prep_clus(const int* __restrict__ clus, const float* __restrict__ clemb,
                          const float* __restrict__ W0, const float* __restrict__ b0,
                          float* __restrict__ ws) {
  __shared__ float ce[H_];
  float* CP = ws + OFF_CP;
  int b = blockIdx.x >> 2, q = blockIdx.x & 3;
  int tid = threadIdx.x;
  int cl = clus[b];
  ce[tid] = clemb[(long long)cl*H_ + tid];
  __syncthreads();
  int ccol = q*256 + tid;
  int G = gcol(ccol>>6, ccol&63);
  float acc = b0[G];
  for (int e = 0; e < H_; ++e) acc = fmaf(ce[e], W0[(E_+e)*FH + G], acc);
  CP[b*FH + ccol] = acc;
}

// ============ sync & staging primitives (pure HIP, no asm) ============
// All h/flag traffic is agent-scope relaxed atomics -> coherent at the MALL,
// no acquire fences anywhere in the loop, so L2 weight lines are never
// invalidated. Ordering: flag store is RELEASE (waits the publishing wave's
// h stores); readers issue h loads after observing the flag (in-order issue).

__device__ __forceinline__ float ld_coh(const float* p) {
  return __hip_atomic_load(p, __ATOMIC_RELAXED, __HIP_MEMORY_SCOPE_AGENT);
}
__device__ __forceinline__ void st_coh(float* p, float v) {
  __hip_atomic_store(p, v, __ATOMIC_RELAXED, __HIP_MEMORY_SCOPE_AGENT);
}

__device__ __forceinline__ void stage8(const float* p, float h[8]) {
  #pragma unroll
  for (int r = 0; r < 8; ++r)
    h[r] = ld_coh(p + r);
}

__device__ __forceinline__ void flag_wait(const unsigned* f, int lane, unsigned tgt) {
  const unsigned* p = f + (lane & 15);
  for (;;) {
    unsigned v = __hip_atomic_load(p, __ATOMIC_RELAXED, __HIP_MEMORY_SCOPE_AGENT);
    if (__all((int)(v >= tgt))) break;
    __builtin_amdgcn_s_sleep(1);
  }
  __atomic_signal_fence(__ATOMIC_SEQ_CST);   // compiler barrier only
}

__device__ __forceinline__ float rl(float v, int src) {
  return __int_as_float(__builtin_amdgcn_readlane(__float_as_int(v), src));
}

__device__ __forceinline__ void lstm_gate(const f4 z, float& cc, float& hh, const bool upd) {
  float ci = sigm(z.x);
  float cj = tanh_(z.y);
  float cf = sigm(z.z + 1.f);
  float co = sigm(z.w);
  float cn = fmaf(cc, cf, ci*cj);
  float hn = tanh_(cn)*co;
  if (upd) { cc = cn; hh = hn; }
}

#define DOT4(X, W) do {                          \
  acc = fmaf((X).x, (W).x, acc);                 \
  acc = fmaf((X).y, (W).y, acc);                 \
  acc = fmaf((X).z, (W).z, acc);                 \
  acc = fmaf((X).w, (W).w, acc); } while (0)

// ============ main persistent kernel ============

__global__ __launch_bounds__(256, 2) void lstm_persist(
    const int* __restrict__ toks, const int* __restrict__ lens,
    const float* __restrict__ decB, float* __restrict__ ws, float* __restrict__ out)
{
  // XCD-colocation swizzle: L2 weight-locality heuristic only (correctness
  // does not depend on placement — all sync is MALL-coherent).
  const int blk  = blockIdx.x;
  const int grp  = ((blk & 7) << 2) | ((blk >> 3) >> 4);  // 0..31
  const int c    = (blk >> 3) & 15;                        // column-WG 0..15
  const int tid  = threadIdx.x;
  const int lane = tid & 63;
  const int wv   = tid >> 6;

  float* ht0g  = ws + OFF_HT0 + grp*(H_*RPG);
  float* ht1g  = ws + OFF_HT1 + grp*(H_*RPG);
  unsigned* fgrp = (unsigned*)(ws + OFF_BAR) + grp*128;
  unsigned* fA = fgrp;          // 16 slots (one 64B line)
  unsigned* fB = fgrp + 32;     // 16 slots
  const float* TP   = ws + OFF_TP;
  const float* CP   = ws + OFF_CP;
  const float* wp0c = ws + OFF_WP0 + c*(64*64*4);
  const float* wp1c = ws + OFF_WP1 + c*(128*64*4);
  const float* dwT  = ws + OFF_DWT;
  const float* b1p  = ws + OFF_B1;

  __shared__ float za[4][8][64];     // z0 partials, 8 KB
  __shared__ float zb[4][8][64];     // z1 partials, 8 KB
  __shared__ float h1sT[8][260];     // h1 transposed for projection (pad 260)
  __shared__ float ldsW[8][260];     // decoderW slice [v][k] (pad 260)
  __shared__ float pred[4][64];      // projection partials

  // stage decoder weight slice (v = c*8 .. c*8+7)
  for (int i = tid; i < 8*H_; i += 256)
    ldsW[i>>8][i&255] = dwT[(c*8 + (i>>8))*H_ + (i&255)];
  __syncthreads();

  // ---- group max length (all lanes) ----
  int Lg = lens[grp*RPG + (lane & 7)];
  Lg = max(Lg, __shfl_xor(Lg, 1));
  Lg = max(Lg, __shfl_xor(Lg, 2));
  Lg = max(Lg, __shfl_xor(Lg, 4));

  // ---- gate-lane constants (wave0 = layer0, wave1 = layer1) ----
  const int gu = lane & 15, q = lane >> 4;   // unit, row-pair selector
  const int rowA = grp*RPG + q, rowB = grp*RPG + q + 4;
  const int lenA = lens[rowA], lenB = lens[rowB];
  const int* tokApt = toks + rowA*T_;
  const int* tokBpt = toks + rowB*T_;
  const f4 cpA = *(const f4*)(CP + rowA*FH + c*64 + gu*4);
  const f4 cpB = *(const f4*)(CP + rowB*FH + c*64 + gu*4);
  const f4 b1v = *(const f4*)(b1p + c*64 + gu*4);
  float* pub0 = ht0g + (c*16 + gu)*RPG;
  float* pub1 = ht1g + (c*16 + gu)*RPG;
  float c0A = 0.f, h0A = 0.f, c0B = 0.f, h0B = 0.f;   // wave0 state
  float c1A = 0.f, h1A = 0.f, c1B = 0.f, h1B = 0.f;   // wave1 state

  // ---- projection constants: wave wv = k-quarter ksub; lane = (pm, pv) ----
  const int pm = lane >> 3, pv = lane & 7;
  const int plen = lens[grp*RPG + pm];
  const float decb = decB[c*8 + pv];
  float* outp = out + (size_t)(grp*RPG + pm)*T_*V_ + c*8 + pv;

  float a0[8], a1[8];
  #pragma unroll
  for (int r = 0; r < 8; ++r) { a0[r] = 0.f; a1[r] = 0.f; }

  for (int t = 0; t < Lg; ++t) {
    const unsigned tgt = (unsigned)(t + 1);

    // ---- S1: reduce z0 partials; layer-0 gates on wave0; publish h0 + flag A ----
    #pragma unroll
    for (int r = 0; r < 8; ++r) za[wv][r][lane] = a0[r];
    __syncthreads();
    if (wv == 0) {
      f4 sA = *(const f4*)&za[0][q][gu*4];
      sA += *(const f4*)&za[1][q][gu*4];
      sA += *(const f4*)&za[2][q][gu*4];
      sA += *(const f4*)&za[3][q][gu*4];
      f4 sB = *(const f4*)&za[0][q+4][gu*4];
      sB += *(const f4*)&za[1][q+4][gu*4];
      sB += *(const f4*)&za[2][q+4][gu*4];
      sB += *(const f4*)&za[3][q+4][gu*4];
      int tokA = tokApt[t], tokB = tokBpt[t];
      f4 zA = sA + *(const f4*)(TP + tokA*FH + c*64 + gu*4) + cpA;
      f4 zB = sB + *(const f4*)(TP + tokB*FH + c*64 + gu*4) + cpB;
      lstm_gate(zA, c0A, h0A, t < lenA);
      lstm_gate(zB, c0B, h0B, t < lenB);
      st_coh(pub0 + q,     h0A);
      st_coh(pub0 + q + 4, h0B);
      if (lane == 0)
        __hip_atomic_store(fA + c, tgt, __ATOMIC_RELEASE, __HIP_MEMORY_SCOPE_AGENT);
    }

    // ---- wait h0(t); stage own quarter to regs; fused a1+=W1lo*h0, a0'=W0*h0 ----
    flag_wait(fA, lane, tgt);
    float hs0[8];
    stage8(ht0g + (wv*64 + lane)*RPG, hs0);
    #pragma unroll
    for (int r = 0; r < 8; ++r) a0[r] = 0.f;
    #pragma unroll 2
    for (int b = 0; b < 16; ++b) {
      const int kb = wv*16 + b;
      const f4 w1 = *(const f4*)(wp1c + kb*256 + lane*4);
      const f4 w0 = *(const f4*)(wp0c + kb*256 + lane*4);
      #pragma unroll
      for (int j = 0; j < 4; ++j) {
        const int src = b*4 + j;
        const float w1j = (j==0)?w1.x:(j==1)?w1.y:(j==2)?w1.z:w1.w;
        const float w0j = (j==0)?w0.x:(j==1)?w0.y:(j==2)?w0.z:w0.w;
        #pragma unroll
        for (int r = 0; r < 8; ++r) {
          float hv = rl(hs0[r], src);
          a1[r] = fmaf(w1j, hv, a1[r]);
          a0[r] = fmaf(w0j, hv, a0[r]);
        }
      }
    }

    // ---- S2: reduce z1 partials; layer-1 gates on wave1; publish h1 + flag B ----
    #pragma unroll
    for (int r = 0; r < 8; ++r) zb[wv][r][lane] = a1[r];
    __syncthreads();
    if (wv == 1) {
      f4 sA = *(const f4*)&zb[0][q][gu*4];
      sA += *(const f4*)&zb[1][q][gu*4];
      sA += *(const f4*)&zb[2][q][gu*4];
      sA += *(const f4*)&zb[3][q][gu*4];
      f4 sB = *(const f4*)&zb[0][q+4][gu*4];
      sB += *(const f4*)&zb[1][q+4][gu*4];
      sB += *(const f4*)&zb[2][q+4][gu*4];
      sB += *(const f4*)&zb[3][q+4][gu*4];
      f4 zA = sA + b1v;
      f4 zB = sB + b1v;
      lstm_gate(zA, c1A, h1A, t < lenA);
      lstm_gate(zB, c1B, h1B, t < lenB);
      st_coh(pub1 + q,     h1A);
      st_coh(pub1 + q + 4, h1B);
      if (lane == 0)
        __hip_atomic_store(fB + c, tgt, __ATOMIC_RELEASE, __HIP_MEMORY_SCOPE_AGENT);
    }

    // ---- wait h1(t); stage own quarter; share to LDS; a1' = W1up*h1 ----
    flag_wait(fB, lane, tgt);
    float hs1[8];
    stage8(ht1g + (wv*64 + lane)*RPG, hs1);
    #pragma unroll
    for (int r = 0; r < 8; ++r) h1sT[r][wv*64 + lane] = hs1[r];
    #pragma unroll
    for (int r = 0; r < 8; ++r) a1[r] = 0.f;
    #pragma unroll 2
    for (int b = 0; b < 16; ++b) {
      const int kb2 = 64 + wv*16 + b;
      const f4 wu = *(const f4*)(wp1c + kb2*256 + lane*4);
      #pragma unroll
      for (int j = 0; j < 4; ++j) {
        const int src = b*4 + j;
        const float wj = (j==0)?wu.x:(j==1)?wu.y:(j==2)?wu.z:wu.w;
        #pragma unroll
        for (int r = 0; r < 8; ++r)
          a1[r] = fmaf(wj, rl(hs1[r], src), a1[r]);
      }
    }
    __syncthreads();   // S3: h1sT complete

    // ---- fused projection: wave wv reduces its k-quarter from h1sT ----
    {
      float acc = 0.f;
      const int kbase = wv*64;
      #pragma unroll 4
      for (int bb = 0; bb < 16; ++bb) {
        const f4 hv4 = *(const f4*)&h1sT[pm][kbase + bb*4];
        const f4 wv4 = *(const f4*)&ldsW[pv][kbase + bb*4];
        DOT4(hv4, wv4);
      }
      pred[wv][lane] = acc;
    }
    __syncthreads();   // S4: pred complete
    if (wv == 2) {
      float tot = pred[0][lane] + pred[1][lane] + pred[2][lane] + pred[3][lane] + decb;
      if (t < plen) outp[(size_t)t*V_] = tot;
    }
  }
}

// ============ launch ============

extern "C" void kernel_launch(void* const* d_in, const int* in_sizes, int n_in,
                              void* d_out, int out_size, void* d_ws, size_t ws_size,
                              hipStream_t stream) {
  const int*   toks  = (const int*)d_in[0];
  const int*   lens  = (const int*)d_in[1];
  const int*   clus  = (const int*)d_in[2];
  const float* cemb  = (const float*)d_in[3];
  const float* clemb = (const float*)d_in[4];
  const float* W0    = (const float*)d_in[5];
  const float* b0    = (const float*)d_in[6];
  const float* W1    = (const float*)d_in[7];
  const float* b1    = (const float*)d_in[8];
  const float* dW    = (const float*)d_in[9];
  const float* decB  = (const float*)d_in[10];
  float* out = (float*)d_out;
  float* ws  = (float*)d_ws;

  // zero output (masked positions must be exactly 0) and the flag block
  hipMemsetAsync(out, 0, (size_t)B_*T_*V_*sizeof(float), stream);
  hipMemsetAsync(ws + OFF_BAR, 0, 4096*sizeof(unsigned), stream);

  prep_pack<<<1024, 256, 0, stream>>>(W0, W1, dW, b1, ws);
  prep_tok <<<V_*4, 256, 0, stream>>>(cemb, W0, ws);
  prep_clus<<<B_*4, 256, 0, stream>>>(clus, clemb, W0, b0, ws);
  lstm_persist<<<NWG, 256, 0, stream>>>(toks, lens, decB, ws, out);
}

// Round 6
// 13387.418 us; speedup vs baseline: 2.4409x; 1.3751x over previous
//
#include <hip/hip_runtime.h>

#define B_ 256
#define T_ 512
#define V_ 128
#define E_ 128
#define H_ 256
#define FH 1024

#define GROUPS 32
#define RPG 8      // batch rows per group
#define CWG 16     // column-WGs per group
#define NWG (GROUPS*CWG)

#define HTG (H_*RPG)          // 2048 floats: one group's h, one buffer
#define GST (GROUPS*HTG)      // one buffer stride

typedef float f4 __attribute__((ext_vector_type(4)));

// ---- workspace layout (float offsets) ----
#define OFF_HT0  0                              // h0 [2buf][grp][256k][8rows]
#define OFF_HT1  (OFF_HT0 + 2*GST)              // h1 same layout
#define OFF_BAR  (OFF_HT1 + 2*GST)              // 32 groups * 128 uints (512B stride)
#define OFF_TP   (OFF_BAR + 4096)               // TokProj [V][1024] packed
#define OFF_CP   (OFF_TP + V_*FH)               // ClusProj [B][1024] packed (+b0)
#define OFF_WP0  (OFF_CP + B_*FH)               // W0h x4-packed [16c][64kb][64lane][4j]
#define OFF_WP1  (OFF_WP0 + CWG*64*64*4)        // W1  x4-packed [16c][128kb][64lane][4j]
#define OFF_DWT  (OFF_WP1 + CWG*128*64*4)       // decoderW^T [128v][256k]
#define OFF_B1   (OFF_DWT + V_*H_)              // b1 packed [1024]

// packed column order: local col = u*4+g  ->  global z-col G = g*256 + c*16 + u
__device__ __forceinline__ int gcol(int c, int col) {
  int u = col >> 2, g = col & 3;
  return g*256 + c*16 + u;
}

__device__ __forceinline__ float sigm(float x){ return 1.f/(1.f+__expf(-x)); }
__device__ __forceinline__ float tanh_(float x){ return 1.f - 2.f/(1.f+__expf(2.f*x)); }

// ============ prep kernels ============

__global__ void prep_pack(const float* __restrict__ W0, const float* __restrict__ W1,
                          const float* __restrict__ dW, const float* __restrict__ b1,
                          float* __restrict__ ws) {
  float* wp0 = ws + OFF_WP0; float* wp1 = ws + OFF_WP1;
  float* dwT = ws + OFF_DWT; float* b1p = ws + OFF_B1;
  const int N0 = CWG*64*64*4;     // 262144
  const int N1 = CWG*128*64*4;    // 524288
  const int N2 = V_*H_;           // 32768
  const int N3 = FH;              // 1024
  const int total = N0+N1+N2+N3;
  for (int i = blockIdx.x*blockDim.x + threadIdx.x; i < total; i += gridDim.x*blockDim.x) {
    if (i < N0) {
      int cc = i >> 14; int rem = i & 16383;
      int kb = rem >> 8; int ln = (rem >> 2) & 63; int j = i & 3;
      int k = kb*4 + j;
      wp0[i] = W0[(E_+H_+k)*FH + gcol(cc, ln)];          // W0 h0-rows
    } else if (i < N0+N1) {
      int idx = i - N0;
      int cc = idx >> 15; int rem = idx & 32767;
      int kb = rem >> 8; int ln = (rem >> 2) & 63; int j = idx & 3;
      int k2 = kb*4 + j;                                  // 0..255 h0n, 256..511 h1
      wp1[idx] = W1[k2*FH + gcol(cc, ln)];
    } else if (i < N0+N1+N2) {
      int l = i - N0 - N1;
      int v = l >> 8, k = l & 255;
      dwT[l] = dW[k*V_ + v];
    } else {
      int cc2 = i - N0 - N1 - N2;
      b1p[cc2] = b1[gcol(cc2>>6, cc2&63)];
    }
  }
}

__global__ void prep_tok(const float* __restrict__ cemb, const float* __restrict__ W0,
                         float* __restrict__ ws) {
  __shared__ float ce[E_];
  float* TP = ws + OFF_TP;
  int v = blockIdx.x >> 2, q = blockIdx.x & 3;
  int tid = threadIdx.x;
  if (tid < E_) ce[tid] = cemb[v*E_ + tid];
  __syncthreads();
  int ccol = q*256 + tid;
  int G = gcol(ccol>>6, ccol&63);
  float acc = 0.f;
  for (int e = 0; e < E_; ++e) acc = fmaf(ce[e], W0[e*FH + G], acc);
  TP[v*FH + ccol] = acc;
}

__global__ void prep_clus(const int* __restrict__ clus, const float* __restrict__ clemb,
                          const float* __restrict__ W0, const float* __restrict__ b0,
                          float* __restrict__ ws) {
  __shared__ float ce[H_];
  float* CP = ws + OFF_CP;
  int b = blockIdx.x >> 2, q = blockIdx.x & 3;
  int tid = threadIdx.x;
  int cl = clus[b];
  ce[tid] = clemb[(long long)cl*H_ + tid];
  __syncthreads();
  int ccol = q*256 + tid;
  int G = gcol(ccol>>6, ccol&63);
  float acc = b0[G];
  for (int e = 0; e < H_; ++e) acc = fmaf(ce[e], W0[(E_+e)*FH + G], acc);
  CP[b*FH + ccol] = acc;
}

// ============ sync & staging primitives (pure HIP, no asm) ============

__device__ __forceinline__ void st_coh(float* p, float v) {
  __hip_atomic_store(p, v, __ATOMIC_RELAXED, __HIP_MEMORY_SCOPE_AGENT);
}

// stage one h row (8 floats, 32B) coherently: 4 x u64 agent-scope loads -> LDS
__device__ __forceinline__ void stage_row(const float* g, float* l) {
  const unsigned long long* p = (const unsigned long long*)g;
  unsigned long long d0 = __hip_atomic_load(p+0, __ATOMIC_RELAXED, __HIP_MEMORY_SCOPE_AGENT);
  unsigned long long d1 = __hip_atomic_load(p+1, __ATOMIC_RELAXED, __HIP_MEMORY_SCOPE_AGENT);
  unsigned long long d2 = __hip_atomic_load(p+2, __ATOMIC_RELAXED, __HIP_MEMORY_SCOPE_AGENT);
  unsigned long long d3 = __hip_atomic_load(p+3, __ATOMIC_RELAXED, __HIP_MEMORY_SCOPE_AGENT);
  float2 f0 = __builtin_bit_cast(float2, d0);
  float2 f1 = __builtin_bit_cast(float2, d1);
  float2 f2 = __builtin_bit_cast(float2, d2);
  float2 f3 = __builtin_bit_cast(float2, d3);
  f4 lo = {f0.x, f0.y, f1.x, f1.y};
  f4 hi = {f2.x, f2.y, f3.x, f3.y};
  *(f4*)(l)     = lo;
  *(f4*)(l + 4) = hi;
}

// wave-0-only poll of the group's 16 flag slots (one 64B line), with backoff
__device__ __forceinline__ void spin16(const unsigned* f, int lane, unsigned tgt) {
  const unsigned* p = f + (lane & 15);
  unsigned v = __hip_atomic_load(p, __ATOMIC_RELAXED, __HIP_MEMORY_SCOPE_AGENT);
  while (!__all((int)(v >= tgt))) {
    __builtin_amdgcn_s_sleep(2);
    v = __hip_atomic_load(p, __ATOMIC_RELAXED, __HIP_MEMORY_SCOPE_AGENT);
  }
}

__device__ __forceinline__ void lstm_gate(const f4 z, float& cc, float& hh, const bool upd) {
  float ci = sigm(z.x);
  float cj = tanh_(z.y);
  float cf = sigm(z.z + 1.f);
  float co = sigm(z.w);
  float cn = fmaf(cc, cf, ci*cj);
  float hn = tanh_(cn)*co;
  if (upd) { cc = cn; hh = hn; }
}

// ============ main persistent kernel ============

__global__ __launch_bounds__(256, 2) void lstm_persist(
    const int* __restrict__ toks, const int* __restrict__ lens,
    const float* __restrict__ decB, float* __restrict__ ws, float* __restrict__ out)
{
  // XCD-colocation swizzle (L2 locality heuristic; correctness is placement-free)
  const int blk  = blockIdx.x;
  const int grp  = ((blk & 7) << 2) | ((blk >> 3) >> 4);  // 0..31
  const int c    = (blk >> 3) & 15;                        // column-WG 0..15
  const int tid  = threadIdx.x;
  const int lane = tid & 63;
  const int wv   = tid >> 6;
  const int cof  = c*64;

  float* ht0 = ws + OFF_HT0;      // [2][GROUPS][HTG]
  float* ht1 = ws + OFF_HT1;
  unsigned* fgrp = (unsigned*)(ws + OFF_BAR) + grp*128;
  unsigned* fA = fgrp;            // 16 slots (one 64B line)
  unsigned* fB = fgrp + 32;       // 16 slots
  const float* TP   = ws + OFF_TP;
  const float* CP   = ws + OFF_CP;
  const float* wp0c = ws + OFF_WP0 + c*(64*64*4);
  const float* wp1c = ws + OFF_WP1 + c*(128*64*4);
  const float* dwT  = ws + OFF_DWT;
  const float* b1p  = ws + OFF_B1;

  __shared__ __align__(16) float h0s[256][8];   // staged h0(t), k-major
  __shared__ __align__(16) float h1s[256][8];   // staged h1(t), k-major
  __shared__ float za[4][8][64];                // z0 partials
  __shared__ float zb[4][8][64];                // z1 partials
  __shared__ float ldsW[8][260];                // decoderW slice [v][k], padded
  __shared__ float pred[4][64];                 // projection partials

  // stage decoder weight slice (v = c*8 .. c*8+7)
  for (int i = tid; i < 8*H_; i += 256)
    ldsW[i>>8][i&255] = dwT[(c*8 + (i>>8))*H_ + (i&255)];

  // staging row index (staggered across c to spread first-touch lines)
  const int sk = (tid + (c << 4)) & 255;

  // ---- group max length (all lanes) ----
  int Lg = lens[grp*RPG + (lane & 7)];
  Lg = max(Lg, __shfl_xor(Lg, 1));
  Lg = max(Lg, __shfl_xor(Lg, 2));
  Lg = max(Lg, __shfl_xor(Lg, 4));

  // ---- gate-lane constants (wave0 = layer0, wave1 = layer1) ----
  const int gu = lane & 15, q = lane >> 4;   // unit, row-pair selector
  const int rowA = grp*RPG + q, rowB = grp*RPG + q + 4;
  const int lenA = lens[rowA], lenB = lens[rowB];
  const int* tokApt = toks + rowA*T_;
  const int* tokBpt = toks + rowB*T_;
  const f4 cpA = *(const f4*)(CP + rowA*FH + cof + gu*4);
  const f4 cpB = *(const f4*)(CP + rowB*FH + cof + gu*4);
  const f4 b1v = *(const f4*)(b1p + cof + gu*4);
  const int puboff = grp*HTG + (c*16 + gu)*8;
  float c0A = 0.f, h0A = 0.f, c0B = 0.f, h0B = 0.f;   // wave0 state
  float c1A = 0.f, h1A = 0.f, c1B = 0.f, h1B = 0.f;   // wave1 state

  // ---- projection constants ----
  const int pm = lane >> 3, pv = lane & 7;
  const int plen = lens[grp*RPG + pm];
  const float decb = decB[c*8 + pv];
  float* outp = out + (size_t)(grp*RPG + pm)*T_*V_ + c*8 + pv;

  float a0[8], a1[8];
  #pragma unroll
  for (int r = 0; r < 8; ++r) { a0[r] = 0.f; a1[r] = 0.f; }

  __syncthreads();   // ldsW staged

  // ---- prologue: S1(0): z0(0) = TP+CP (no h term); publish h0(0) buf0, fA=1 ----
  if (wv == 0) {
    int tokA = tokApt[0], tokB = tokBpt[0];
    f4 zA = *(const f4*)(TP + tokA*FH + cof + gu*4) + cpA;
    f4 zB = *(const f4*)(TP + tokB*FH + cof + gu*4) + cpB;
    lstm_gate(zA, c0A, h0A, 0 < lenA);
    lstm_gate(zB, c0B, h0B, 0 < lenB);
    float* pb = ht0 + puboff;
    st_coh(pb + q,     h0A);
    st_coh(pb + q + 4, h0B);
    if (lane == 0)
      __hip_atomic_store(fA + c, 1u, __ATOMIC_RELEASE, __HIP_MEMORY_SCOPE_AGENT);
  }

  for (int t = 0; t < Lg; ++t) {
    const int buf = t & 1;

    // ---- waitA(t): wave0 polls, others park at the barrier ----
    if (wv == 0) spin16(fA, lane, (unsigned)(t + 1));
    __syncthreads();                                   // (1)
    __atomic_signal_fence(__ATOMIC_SEQ_CST);

    // ---- stage h0(t) -> LDS ----
    stage_row(ht0 + buf*GST + grp*HTG + sk*8, &h0s[sk][0]);
    __syncthreads();                                   // (2)

    // ---- phase1: a0 = W0*h0(t); a1 += W1lo*h0(t)  (h via LDS broadcast) ----
    #pragma unroll
    for (int r = 0; r < 8; ++r) a0[r] = 0.f;
    #pragma unroll 2
    for (int b = 0; b < 16; ++b) {
      const int kb = wv*16 + b;
      const f4 w1 = *(const f4*)(wp1c + kb*256 + lane*4);
      const f4 w0 = *(const f4*)(wp0c + kb*256 + lane*4);
      const float* w1a = (const float*)&w1;
      const float* w0a = (const float*)&w0;
      #pragma unroll
      for (int j = 0; j < 4; ++j) {
        const int k = kb*4 + j;
        const f4 ha = *(const f4*)&h0s[k][0];
        const f4 hb = *(const f4*)&h0s[k][4];
        const float w1j = w1a[j], w0j = w0a[j];
        a0[0]=fmaf(w0j,ha.x,a0[0]); a0[1]=fmaf(w0j,ha.y,a0[1]);
        a0[2]=fmaf(w0j,ha.z,a0[2]); a0[3]=fmaf(w0j,ha.w,a0[3]);
        a0[4]=fmaf(w0j,hb.x,a0[4]); a0[5]=fmaf(w0j,hb.y,a0[5]);
        a0[6]=fmaf(w0j,hb.z,a0[6]); a0[7]=fmaf(w0j,hb.w,a0[7]);
        a1[0]=fmaf(w1j,ha.x,a1[0]); a1[1]=fmaf(w1j,ha.y,a1[1]);
        a1[2]=fmaf(w1j,ha.z,a1[2]); a1[3]=fmaf(w1j,ha.w,a1[3]);
        a1[4]=fmaf(w1j,hb.x,a1[4]); a1[5]=fmaf(w1j,hb.y,a1[5]);
        a1[6]=fmaf(w1j,hb.z,a1[6]); a1[7]=fmaf(w1j,hb.w,a1[7]);
      }
    }

    // ---- S1(t+1): gates L0 for next step, publish h0(t+1) early (pre-signal A) ----
    if (t + 1 < Lg) {
      #pragma unroll
      for (int r = 0; r < 8; ++r) za[wv][r][lane] = a0[r];
      __syncthreads();                                 // (3)
      if (wv == 0) {
        f4 sA = *(const f4*)&za[0][q][gu*4];
        sA += *(const f4*)&za[1][q][gu*4];
        sA += *(const f4*)&za[2][q][gu*4];
        sA += *(const f4*)&za[3][q][gu*4];
        f4 sB = *(const f4*)&za[0][q+4][gu*4];
        sB += *(const f4*)&za[1][q+4][gu*4];
        sB += *(const f4*)&za[2][q+4][gu*4];
        sB += *(const f4*)&za[3][q+4][gu*4];
        int tokA = tokApt[t+1], tokB = tokBpt[t+1];
        f4 zA = sA + *(const f4*)(TP + tokA*FH + cof + gu*4) + cpA;
        f4 zB = sB + *(const f4*)(TP + tokB*FH + cof + gu*4) + cpB;
        lstm_gate(zA, c0A, h0A, (t+1) < lenA);
        lstm_gate(zB, c0B, h0B, (t+1) < lenB);
        float* pb = ht0 + (buf^1)*GST + puboff;
        st_coh(pb + q,     h0A);
        st_coh(pb + q + 4, h0B);
        if (lane == 0)
          __hip_atomic_store(fA + c, (unsigned)(t + 2), __ATOMIC_RELEASE, __HIP_MEMORY_SCOPE_AGENT);
      }
    }

    // ---- S2(t): gates L1, publish h1(t), flag B ----
    #pragma unroll
    for (int r = 0; r < 8; ++r) zb[wv][r][lane] = a1[r];
    __syncthreads();                                   // (4)
    if (wv == 1) {
      f4 sA = *(const f4*)&zb[0][q][gu*4];
      sA += *(const f4*)&zb[1][q][gu*4];
      sA += *(const f4*)&zb[2][q][gu*4];
      sA += *(const f4*)&zb[3][q][gu*4];
      f4 sB = *(const f4*)&zb[0][q+4][gu*4];
      sB += *(const f4*)&zb[1][q+4][gu*4];
      sB += *(const f4*)&zb[2][q+4][gu*4];
      sB += *(const f4*)&zb[3][q+4][gu*4];
      f4 zA = sA + b1v;
      f4 zB = sB + b1v;
      lstm_gate(zA, c1A, h1A, t < lenA);
      lstm_gate(zB, c1B, h1B, t < lenB);
      float* pb = ht1 + buf*GST + puboff;
      st_coh(pb + q,     h1A);
      st_coh(pb + q + 4, h1B);
      if (lane == 0)
        __hip_atomic_store(fB + c, (unsigned)(t + 1), __ATOMIC_RELEASE, __HIP_MEMORY_SCOPE_AGENT);
    }

    // ---- waitB(t) ----
    if (wv == 0) spin16(fB, lane, (unsigned)(t + 1));
    __syncthreads();                                   // (5)
    __atomic_signal_fence(__ATOMIC_SEQ_CST);

    // ---- stage h1(t) -> LDS ----
    stage_row(ht1 + buf*GST + grp*HTG + sk*8, &h1s[sk][0]);
    __syncthreads();                                   // (6)

    // ---- phase2: a1 = W1up*h1(t)  (carry into next step's S2) ----
    #pragma unroll
    for (int r = 0; r < 8; ++r) a1[r] = 0.f;
    #pragma unroll 2
    for (int b = 0; b < 16; ++b) {
      const int kb = wv*16 + b;
      const f4 wu = *(const f4*)(wp1c + (64 + kb)*256 + lane*4);
      const float* wua = (const float*)&wu;
      #pragma unroll
      for (int j = 0; j < 4; ++j) {
        const int k = kb*4 + j;
        const f4 ha = *(const f4*)&h1s[k][0];
        const f4 hb = *(const f4*)&h1s[k][4];
        const float wj = wua[j];
        a1[0]=fmaf(wj,ha.x,a1[0]); a1[1]=fmaf(wj,ha.y,a1[1]);
        a1[2]=fmaf(wj,ha.z,a1[2]); a1[3]=fmaf(wj,ha.w,a1[3]);
        a1[4]=fmaf(wj,hb.x,a1[4]); a1[5]=fmaf(wj,hb.y,a1[5]);
        a1[6]=fmaf(wj,hb.z,a1[6]); a1[7]=fmaf(wj,hb.w,a1[7]);
      }
    }

    // ---- projection(t): out[b][t][c*8+pv], 4-way k-split over waves ----
    {
      float acc = 0.f;
      const int kq = wv*64;
      #pragma unroll 4
      for (int k2 = 0; k2 < 64; k2 += 4) {
        const f4 w4 = *(const f4*)&ldsW[pv][kq + k2];
        acc = fmaf(h1s[kq+k2  ][pm], w4.x, acc);
        acc = fmaf(h1s[kq+k2+1][pm], w4.y, acc);
        acc = fmaf(h1s[kq+k2+2][pm], w4.z, acc);
        acc = fmaf(h1s[kq+k2+3][pm], w4.w, acc);
      }
      pred[wv][lane] = acc;
    }
    __syncthreads();                                   // (7)
    if (wv == 2) {
      float tot = pred[0][lane] + pred[1][lane] + pred[2][lane] + pred[3][lane] + decb;
      if (t < plen) outp[(size_t)t*V_] = tot;
    }
  }
}

// ============ launch ============

extern "C" void kernel_launch(void* const* d_in, const int* in_sizes, int n_in,
                              void* d_out, int out_size, void* d_ws, size_t ws_size,
                              hipStream_t stream) {
  const int*   toks  = (const int*)d_in[0];
  const int*   lens  = (const int*)d_in[1];
  const int*   clus  = (const int*)d_in[2];
  const float* cemb  = (const float*)d_in[3];
  const float* clemb = (const float*)d_in[4];
  const float* W0    = (const float*)d_in[5];
  const float* b0    = (const float*)d_in[6];
  const float* W1    = (const float*)d_in[7];
  const float* b1    = (const float*)d_in[8];
  const float* dW    = (const float*)d_in[9];
  const float* decB  = (const float*)d_in[10];
  float* out = (float*)d_out;
  float* ws  = (float*)d_ws;

  // zero output (masked positions must be exactly 0) and the flag block
  hipMemsetAsync(out, 0, (size_t)B_*T_*V_*sizeof(float), stream);
  hipMemsetAsync(ws + OFF_BAR, 0, 4096*sizeof(unsigned), stream);

  prep_pack<<<1024, 256, 0, stream>>>(W0, W1, dW, b1, ws);
  prep_tok <<<V_*4, 256, 0, stream>>>(cemb, W0, ws);
  prep_clus<<<B_*4, 256, 0, stream>>>(clus, clemb, W0, b0, ws);
  lstm_persist<<<NWG, 256, 0, stream>>>(toks, lens, decB, ws, out);
}